// Round 2
// baseline (595.442 us; speedup 1.0000x reference)
//
#include <hip/hip_runtime.h>
#include <hip/hip_bf16.h>

// GAT layer, N=8192, F_IN=256, F_OUT=128.
// K1: Wh = h@W (fp32) + WhT (f16, transposed [c][j] for contiguous MFMA B-frags)
// K2: f1 = Wh@a1, f2 = Wh@a2
// K3: fused masked-softmax attention + PV via f16 MFMA 16x16x32.
//     p' = 2^-16 * exp(leaky(f1_i+f2_j)) (scale cancels in num/den; keeps p' in f16 range)
//     out_i = (sum_j f16(p'_ij) * f16(Wh_j)) / (sum_j f16(p'_ij))   -- consistent rounding
//     Runtime C/D-layout probe (2 identity MFMAs) makes the output scatter
//     self-correcting against C/D or B-col layout misassumptions.
// Scratch in __device__ globals (d_ws size never verified -> avoid it entirely).

#define N_NODES 8192
#define F_IN 256
#define F_OUT 128

typedef _Float16 half8 __attribute__((ext_vector_type(8)));
typedef float floatx4 __attribute__((ext_vector_type(4)));

__device__ __align__(16) float g_Wh[N_NODES * F_OUT];                 // 4 MB
__device__ __align__(16) _Float16 g_WhT[(size_t)F_OUT * N_NODES];     // 2 MB
__device__ __align__(16) float g_f1[N_NODES];
__device__ __align__(16) float g_f2[N_NODES];

// ---------------- Kernel A: Wh = h @ W ----------------
__global__ __launch_bounds__(256) void wh_kernel(
    const float* __restrict__ h, const float* __restrict__ W) {
  __shared__ float hT[F_IN][36];  // transposed h tile (+pad keeps 16B alignment)
  const int t = threadIdx.x;
  const int i0 = blockIdx.x * 32;
  {
    const int lr = t >> 6;         // 0..3
    const int kc = (t & 63) * 4;   // 0..252
    for (int m = 0; m < 8; ++m) {
      const int row = m * 4 + lr;  // 0..31
      const float4 v = *(const float4*)(h + (size_t)(i0 + row) * F_IN + kc);
      hT[kc + 0][row] = v.x; hT[kc + 1][row] = v.y;
      hT[kc + 2][row] = v.z; hT[kc + 3][row] = v.w;
    }
  }
  __syncthreads();
  const int c = t & 127;   // output col
  const int rg = t >> 7;   // row group: 16 rows each
  float acc[16];
#pragma unroll
  for (int r = 0; r < 16; ++r) acc[r] = 0.f;
  for (int k = 0; k < F_IN; ++k) {
    const float wv = W[k * F_OUT + c];  // coalesced, L2-hot
    const float4* hp = (const float4*)(&hT[k][rg * 16]);  // lane-uniform -> LDS broadcast
    float4 x0 = hp[0], x1 = hp[1], x2 = hp[2], x3 = hp[3];
    acc[0] = fmaf(x0.x, wv, acc[0]);   acc[1] = fmaf(x0.y, wv, acc[1]);
    acc[2] = fmaf(x0.z, wv, acc[2]);   acc[3] = fmaf(x0.w, wv, acc[3]);
    acc[4] = fmaf(x1.x, wv, acc[4]);   acc[5] = fmaf(x1.y, wv, acc[5]);
    acc[6] = fmaf(x1.z, wv, acc[6]);   acc[7] = fmaf(x1.w, wv, acc[7]);
    acc[8] = fmaf(x2.x, wv, acc[8]);   acc[9] = fmaf(x2.y, wv, acc[9]);
    acc[10] = fmaf(x2.z, wv, acc[10]); acc[11] = fmaf(x2.w, wv, acc[11]);
    acc[12] = fmaf(x3.x, wv, acc[12]); acc[13] = fmaf(x3.y, wv, acc[13]);
    acc[14] = fmaf(x3.z, wv, acc[14]); acc[15] = fmaf(x3.w, wv, acc[15]);
  }
#pragma unroll
  for (int r = 0; r < 16; ++r)
    g_Wh[(size_t)(i0 + rg * 16 + r) * F_OUT + c] = acc[r];
  // f16 transposed copy: g_WhT[c][i0 + rg*16 .. +15], 32B contiguous per thread
  union { _Float16 hh[16]; uint4 u4[2]; } pk;
#pragma unroll
  for (int r = 0; r < 16; ++r) pk.hh[r] = (_Float16)acc[r];
  uint4* dst = (uint4*)(g_WhT + (size_t)c * N_NODES + i0 + rg * 16);
  dst[0] = pk.u4[0];
  dst[1] = pk.u4[1];
}

// ---------------- Kernel B: f1 = Wh@a1, f2 = Wh@a2 ----------------
__global__ __launch_bounds__(256) void f12_kernel(const float* __restrict__ a) {
  const int t = threadIdx.x;
  const int row = blockIdx.x * 2 + (t >> 7);
  const int c = t & 127;
  const float wh = g_Wh[(size_t)row * F_OUT + c];
  float p1 = wh * a[c];
  float p2 = wh * a[F_OUT + c];
  for (int o = 32; o > 0; o >>= 1) {
    p1 += __shfl_down(p1, o, 64);
    p2 += __shfl_down(p2, o, 64);
  }
  __shared__ float s1[4], s2[4];
  const int w = t >> 6;
  if ((t & 63) == 0) { s1[w] = p1; s2[w] = p2; }
  __syncthreads();
  if ((t & 127) == 0) {
    g_f1[row] = s1[w] + s1[w + 1];
    g_f2[row] = s2[w] + s2[w + 1];
  }
}

// ---------------- Kernel C: fused attention ----------------
// p' = adj>0 ? 2^-16 * exp(leaky_relu(f1_i + f2_j)) : 0
__device__ __forceinline__ float score_p(int a, float f2v, float f1r) {
  float s = f1r + f2v;
  s = fmaxf(s, 0.2f * s);  // leaky_relu, alpha=0.2 < 1
  float arg = (a > 0) ? fmaf(s, 1.44269504088896f, -16.0f) : -1.0e5f;
  return __builtin_amdgcn_exp2f(arg);  // masked -> 0
}

__global__ __launch_bounds__(256) void gat_attn_kernel(
    const int* __restrict__ adj, float* __restrict__ out) {
  const int t = threadIdx.x;
  const int wave = t >> 6;
  const int lane = t & 63;
  const int mrow = lane & 15;   // A-operand row (= graph row in tile)
  const int quad = lane >> 4;   // k-subgroup: k = quad*8 + e
  const int i0 = blockIdx.x * 16;
  const int row = i0 + mrow;
  const float f1r = g_f1[row];
  const size_t adj_row = (size_t)row * N_NODES;

  // --- runtime C/D layout probe: D1[m][n] = m, D2[m][n] = n ---
  int rm[4], cm[4];
  {
    half8 a1f, b1f, a2f, b2f;
#pragma unroll
    for (int e = 0; e < 8; ++e) {
      a1f[e] = (_Float16)0; b1f[e] = (_Float16)0;
      a2f[e] = (_Float16)0; b2f[e] = (_Float16)0;
    }
    if (quad == 0) {             // k==0 element lives in quad 0, e==0
      a1f[0] = (_Float16)mrow;   // A1[m][0] = m
      b1f[0] = (_Float16)1;      // B1[0][n] = 1
      a2f[0] = (_Float16)1;      // A2[m][0] = 1
      b2f[0] = (_Float16)mrow;   // B2[0][n] = n
    }
    floatx4 d1 = (floatx4)0.f, d2 = (floatx4)0.f;
    d1 = __builtin_amdgcn_mfma_f32_16x16x32_f16(a1f, b1f, d1, 0, 0, 0);
    d2 = __builtin_amdgcn_mfma_f32_16x16x32_f16(a2f, b2f, d2, 0, 0, 0);
#pragma unroll
    for (int r = 0; r < 4; ++r) { rm[r] = (int)d1[r]; cm[r] = (int)d2[r]; }
  }

  floatx4 acc[8];  // 8 col-tiles of 16 -> 128 output cols
#pragma unroll
  for (int ct = 0; ct < 8; ++ct) acc[ct] = (floatx4)0.f;
  float psum = 0.f;

  const int jbeg = wave * 2048;
  const int jend = jbeg + 2048;
  const int qoff = quad * 8;

  // one-deep prefetch of adj + f2
  int4 ca0 = *(const int4*)(adj + adj_row + jbeg + qoff);
  int4 ca1 = *(const int4*)(adj + adj_row + jbeg + qoff + 4);
  float4 cg0 = *(const float4*)(g_f2 + jbeg + qoff);
  float4 cg1 = *(const float4*)(g_f2 + jbeg + qoff + 4);

  for (int j0 = jbeg; j0 < jend; j0 += 32) {
    const int jn = (j0 + 32 < jend) ? (j0 + 32) : jbeg;
    int4 na0 = *(const int4*)(adj + adj_row + jn + qoff);
    int4 na1 = *(const int4*)(adj + adj_row + jn + qoff + 4);
    float4 ng0 = *(const float4*)(g_f2 + jn + qoff);
    float4 ng1 = *(const float4*)(g_f2 + jn + qoff + 4);

    float p[8];
    p[0] = score_p(ca0.x, cg0.x, f1r);
    p[1] = score_p(ca0.y, cg0.y, f1r);
    p[2] = score_p(ca0.z, cg0.z, f1r);
    p[3] = score_p(ca0.w, cg0.w, f1r);
    p[4] = score_p(ca1.x, cg1.x, f1r);
    p[5] = score_p(ca1.y, cg1.y, f1r);
    p[6] = score_p(ca1.z, cg1.z, f1r);
    p[7] = score_p(ca1.w, cg1.w, f1r);

    half8 af;
#pragma unroll
    for (int e = 0; e < 8; ++e) {
      const _Float16 hf = (_Float16)p[e];
      af[e] = hf;
      psum += (float)hf;  // denominator uses the SAME rounded values as numerator
    }

    const int kbase = j0 + qoff;
#pragma unroll
    for (int ct = 0; ct < 8; ++ct) {
      const half8 bfr =
          *(const half8*)(g_WhT + (size_t)(ct * 16 + mrow) * N_NODES + kbase);
      acc[ct] = __builtin_amdgcn_mfma_f32_16x16x32_f16(af, bfr, acc[ct], 0, 0, 0);
    }
    ca0 = na0; ca1 = na1; cg0 = ng0; cg1 = ng1;
  }

  // row-sum: combine the 4 k-quads (rows rely only on A-layout m=lane&15)
  psum += __shfl_xor(psum, 16, 64);
  psum += __shfl_xor(psum, 32, 64);

  __shared__ float ldsO[4][16][128];
  __shared__ float ldsS[4][16];
#pragma unroll
  for (int ct = 0; ct < 8; ++ct)
#pragma unroll
    for (int r = 0; r < 4; ++r)
      ldsO[wave][rm[r]][ct * 16 + cm[r]] = acc[ct][r];  // probed C/D mapping
  if (lane < 16) ldsS[wave][lane] = psum;
  __syncthreads();

  // combine 4 wave-partials (j-split), normalize, write out
  {
    const int r = t >> 4;
    const int c0 = (t & 15) * 8;
    const float s = ldsS[0][r] + ldsS[1][r] + ldsS[2][r] + ldsS[3][r];
    const float inv = 1.0f / s;
    float o[8];
#pragma unroll
    for (int q = 0; q < 8; ++q)
      o[q] = (ldsO[0][r][c0 + q] + ldsO[1][r][c0 + q] +
              ldsO[2][r][c0 + q] + ldsO[3][r][c0 + q]) * inv;
    float4* dst = (float4*)(out + (size_t)(i0 + r) * F_OUT + c0);
    dst[0] = make_float4(o[0], o[1], o[2], o[3]);
    dst[1] = make_float4(o[4], o[5], o[6], o[7]);
  }
}

extern "C" void kernel_launch(void* const* d_in, const int* in_sizes, int n_in,
                              void* d_out, int out_size, void* d_ws, size_t ws_size,
                              hipStream_t stream) {
  const float* h = (const float*)d_in[0];
  const int* adj = (const int*)d_in[1];
  const float* W = (const float*)d_in[2];
  const float* a = (const float*)d_in[3];
  float* out = (float*)d_out;
  (void)d_ws; (void)ws_size;

  wh_kernel<<<dim3(N_NODES / 32), dim3(256), 0, stream>>>(h, W);
  f12_kernel<<<dim3(N_NODES / 2), dim3(256), 0, stream>>>(a);
  gat_attn_kernel<<<dim3(N_NODES / 16), dim3(256), 0, stream>>>(adj, out);
}

// Round 3
// 570.718 us; speedup vs baseline: 1.0433x; 1.0433x over previous
//
#include <hip/hip_runtime.h>

// GAT layer, N=8192, F_IN=256, F_OUT=128.
// K1 wh: Wh = h@W (fp32) + WhT (f16 transposed [c][j]) ; K2: f1,f2 ; 
// K3 attn: 32-row blocks x JSPLIT=4 j-split; per wave: 2 A-tiles, 16 k-steps.
//   adj: nontemporal 2-deep prefetch (3 bufs). B-frags: double-buffered, issued
//   FIRST each iter so vmcnt-FIFO waits on B don't drain the adj prefetch.
//   psum via ones-column MFMA. Partials -> g_part scratch. K4 comb: normalize.

#define N_NODES 8192
#define F_IN 256
#define F_OUT 128
#define ROWS_PB 32
#define JSPLIT 4
#define BLK_J (N_NODES / JSPLIT)   // 2048
#define WAVE_J (BLK_J / 4)         // 512
#define NK (WAVE_J / 32)           // 16 k-steps per wave

typedef _Float16 half8 __attribute__((ext_vector_type(8)));
typedef float floatx4 __attribute__((ext_vector_type(4)));
typedef int i32x4 __attribute__((ext_vector_type(4)));
typedef float f32x4 __attribute__((ext_vector_type(4)));

__device__ __align__(16) float g_Wh[N_NODES * F_OUT];                  // 4 MB
__device__ __align__(16) _Float16 g_WhT[(size_t)F_OUT * N_NODES];      // 2 MB
__device__ __align__(16) float g_f1[N_NODES];
__device__ __align__(16) float g_f2[N_NODES];
__device__ __align__(16) float g_part[JSPLIT][N_NODES * F_OUT];        // 16 MB
__device__ __align__(16) float g_spart[JSPLIT][N_NODES];               // 128 KB

// ---------------- Kernel A: Wh = h @ W ----------------
__global__ __launch_bounds__(256) void wh_kernel(
    const float* __restrict__ h, const float* __restrict__ W) {
  __shared__ float hT[F_IN][36];
  const int t = threadIdx.x;
  const int i0 = blockIdx.x * 32;
  {
    const int lr = t >> 6;
    const int kc = (t & 63) * 4;
    for (int m = 0; m < 8; ++m) {
      const int row = m * 4 + lr;
      const float4 v = *(const float4*)(h + (size_t)(i0 + row) * F_IN + kc);
      hT[kc + 0][row] = v.x; hT[kc + 1][row] = v.y;
      hT[kc + 2][row] = v.z; hT[kc + 3][row] = v.w;
    }
  }
  __syncthreads();
  const int c = t & 127;
  const int rg = t >> 7;
  float acc[16];
#pragma unroll
  for (int r = 0; r < 16; ++r) acc[r] = 0.f;
#pragma unroll 4
  for (int k = 0; k < F_IN; ++k) {
    const float wv = W[k * F_OUT + c];
    const float4* hp = (const float4*)(&hT[k][rg * 16]);
    float4 x0 = hp[0], x1 = hp[1], x2 = hp[2], x3 = hp[3];
    acc[0] = fmaf(x0.x, wv, acc[0]);   acc[1] = fmaf(x0.y, wv, acc[1]);
    acc[2] = fmaf(x0.z, wv, acc[2]);   acc[3] = fmaf(x0.w, wv, acc[3]);
    acc[4] = fmaf(x1.x, wv, acc[4]);   acc[5] = fmaf(x1.y, wv, acc[5]);
    acc[6] = fmaf(x1.z, wv, acc[6]);   acc[7] = fmaf(x1.w, wv, acc[7]);
    acc[8] = fmaf(x2.x, wv, acc[8]);   acc[9] = fmaf(x2.y, wv, acc[9]);
    acc[10] = fmaf(x2.z, wv, acc[10]); acc[11] = fmaf(x2.w, wv, acc[11]);
    acc[12] = fmaf(x3.x, wv, acc[12]); acc[13] = fmaf(x3.y, wv, acc[13]);
    acc[14] = fmaf(x3.z, wv, acc[14]); acc[15] = fmaf(x3.w, wv, acc[15]);
  }
#pragma unroll
  for (int r = 0; r < 16; ++r)
    g_Wh[(size_t)(i0 + rg * 16 + r) * F_OUT + c] = acc[r];
  union { _Float16 hh[16]; uint4 u4[2]; } pk;
#pragma unroll
  for (int r = 0; r < 16; ++r) pk.hh[r] = (_Float16)acc[r];
  uint4* dst = (uint4*)(g_WhT + (size_t)c * N_NODES + i0 + rg * 16);
  dst[0] = pk.u4[0];
  dst[1] = pk.u4[1];
}

// ---------------- Kernel B: f1 = Wh@a1, f2 = Wh@a2 ----------------
__global__ __launch_bounds__(256) void f12_kernel(const float* __restrict__ a) {
  const int t = threadIdx.x;
  const int row = blockIdx.x * 2 + (t >> 7);
  const int c = t & 127;
  const float wh = g_Wh[(size_t)row * F_OUT + c];
  float p1 = wh * a[c];
  float p2 = wh * a[F_OUT + c];
  for (int o = 32; o > 0; o >>= 1) {
    p1 += __shfl_down(p1, o, 64);
    p2 += __shfl_down(p2, o, 64);
  }
  __shared__ float s1[4], s2[4];
  const int w = t >> 6;
  if ((t & 63) == 0) { s1[w] = p1; s2[w] = p2; }
  __syncthreads();
  if ((t & 127) == 0) {
    g_f1[row] = s1[w] + s1[w + 1];
    g_f2[row] = s2[w] + s2[w + 1];
  }
}

// ---------------- Kernel C: fused attention (partials) ----------------
__device__ __forceinline__ float score_p(int a, float f2v, float f1r) {
  float s = f1r + f2v;
  s = fmaxf(s, 0.2f * s);
  float arg = (a > 0) ? fmaf(s, 1.44269504088896f, -16.0f) : -1.0e5f;
  return __builtin_amdgcn_exp2f(arg);
}

__global__ __launch_bounds__(256, 2) void gat_attn_kernel(const int* __restrict__ adj) {
  const int t = threadIdx.x;
  const int wave = t >> 6;
  const int lane = t & 63;
  const int mrow = lane & 15;
  const int quad = lane >> 4;
  const int i0 = blockIdx.x * ROWS_PB;
  const int js = blockIdx.y;
  const int jwb = js * BLK_J + wave * WAVE_J;

  const int r0 = i0 + mrow;
  const int r1 = r0 + 16;
  const float f1r0 = g_f1[r0];
  const float f1r1 = g_f1[r1];
  const int qoff = quad * 8;

  // runtime C/D layout probe: D1[m][n]=m, D2[m][n]=n
  int rm[4], cm[4];
  {
    half8 a1f, b1f, a2f, b2f;
#pragma unroll
    for (int e = 0; e < 8; ++e) {
      a1f[e] = (_Float16)0; b1f[e] = (_Float16)0;
      a2f[e] = (_Float16)0; b2f[e] = (_Float16)0;
    }
    if (quad == 0) {
      a1f[0] = (_Float16)mrow; b1f[0] = (_Float16)1;
      a2f[0] = (_Float16)1;    b2f[0] = (_Float16)mrow;
    }
    floatx4 d1 = (floatx4)0.f, d2 = (floatx4)0.f;
    d1 = __builtin_amdgcn_mfma_f32_16x16x32_f16(a1f, b1f, d1, 0, 0, 0);
    d2 = __builtin_amdgcn_mfma_f32_16x16x32_f16(a2f, b2f, d2, 0, 0, 0);
#pragma unroll
    for (int r = 0; r < 4; ++r) { rm[r] = (int)d1[r]; cm[r] = (int)d2[r]; }
  }

  half8 ones;
#pragma unroll
  for (int e = 0; e < 8; ++e) ones[e] = (_Float16)1;

  floatx4 acc[2][8];
  floatx4 asum[2];
#pragma unroll
  for (int tl = 0; tl < 2; ++tl) {
    asum[tl] = (floatx4)0.f;
#pragma unroll
    for (int ct = 0; ct < 8; ++ct) acc[tl][ct] = (floatx4)0.f;
  }

  const i32x4* ap0 = (const i32x4*)(adj + (size_t)r0 * N_NODES + jwb + qoff);
  const i32x4* ap1 = (const i32x4*)(adj + (size_t)r1 * N_NODES + jwb + qoff);
  const f32x4* fp  = (const f32x4*)(g_f2 + jwb + qoff);
  const _Float16* bp = g_WhT + (size_t)mrow * N_NODES + jwb + qoff;

  i32x4 a0b[3][2], a1b[3][2];
  f32x4 f2b[3][2];
  half8 Bb[2][8];

#define LDADJ(tt, buf) do { \
    a0b[buf][0] = __builtin_nontemporal_load(ap0 + (tt) * 8); \
    a0b[buf][1] = __builtin_nontemporal_load(ap0 + (tt) * 8 + 1); \
    a1b[buf][0] = __builtin_nontemporal_load(ap1 + (tt) * 8); \
    a1b[buf][1] = __builtin_nontemporal_load(ap1 + (tt) * 8 + 1); \
    f2b[buf][0] = fp[(tt) * 8]; \
    f2b[buf][1] = fp[(tt) * 8 + 1]; \
  } while (0)

#define LDB(tt, buf) do { \
    _Pragma("unroll") \
    for (int ct = 0; ct < 8; ++ct) \
      Bb[buf][ct] = *(const half8*)(bp + (size_t)ct * 16 * N_NODES + (tt) * 32); \
  } while (0)

  LDADJ(0, 0);
  LDB(0, 0);
  LDADJ(1, 1);

  for (int k = 0; k < NK; ++k) {
    // issue order matters (vmcnt FIFO): B(k+1) first, then adj(k+2);
    // the wait on B(k) then leaves adj(k+1),adj(k+2),B(k+1) in flight.
    if (k + 1 < NK) LDB(k + 1, (k + 1) & 1);
    if (k + 2 < NK) LDADJ(k + 2, (k + 2) % 3);

    const int b = k % 3;
    half8 af0, af1;
#pragma unroll
    for (int e = 0; e < 4; ++e) {
      af0[e]     = (_Float16)score_p(a0b[b][0][e], f2b[b][0][e], f1r0);
      af0[4 + e] = (_Float16)score_p(a0b[b][1][e], f2b[b][1][e], f1r0);
      af1[e]     = (_Float16)score_p(a1b[b][0][e], f2b[b][0][e], f1r1);
      af1[4 + e] = (_Float16)score_p(a1b[b][1][e], f2b[b][1][e], f1r1);
    }

    const int bb = k & 1;
#pragma unroll
    for (int ct = 0; ct < 8; ++ct) {
      acc[0][ct] = __builtin_amdgcn_mfma_f32_16x16x32_f16(af0, Bb[bb][ct], acc[0][ct], 0, 0, 0);
      acc[1][ct] = __builtin_amdgcn_mfma_f32_16x16x32_f16(af1, Bb[bb][ct], acc[1][ct], 0, 0, 0);
    }
    asum[0] = __builtin_amdgcn_mfma_f32_16x16x32_f16(af0, ones, asum[0], 0, 0, 0);
    asum[1] = __builtin_amdgcn_mfma_f32_16x16x32_f16(af1, ones, asum[1], 0, 0, 0);
  }
#undef LDADJ
#undef LDB

  __shared__ float ldsO[ROWS_PB][F_OUT];   // 16 KB
  __shared__ float ldsS[4][ROWS_PB];       // 512 B

  if (mrow == 0) {
#pragma unroll
    for (int tl = 0; tl < 2; ++tl)
#pragma unroll
      for (int r = 0; r < 4; ++r)
        ldsS[wave][tl * 16 + rm[r]] = asum[tl][r];
  }
  // serialized wave-add into shared 32x128 tile
  for (int w = 0; w < 4; ++w) {
    if (wave == w) {
#pragma unroll
      for (int tl = 0; tl < 2; ++tl)
#pragma unroll
        for (int ct = 0; ct < 8; ++ct)
#pragma unroll
          for (int r = 0; r < 4; ++r) {
            float* p = &ldsO[tl * 16 + rm[r]][ct * 16 + cm[r]];
            if (w == 0) *p = acc[tl][ct][r];
            else        *p += acc[tl][ct][r];
          }
    }
    __syncthreads();
  }
  // write partials: thread t -> row t>>3, cols (t&7)*16 .. +15
  {
    const int row = t >> 3;
    const int c0 = (t & 7) * 16;
    float* dst = g_part[js] + (size_t)(i0 + row) * F_OUT + c0;
#pragma unroll
    for (int q = 0; q < 4; ++q)
      *(f32x4*)(dst + q * 4) = *(const f32x4*)(&ldsO[row][c0 + q * 4]);
    if (t < ROWS_PB)
      g_spart[js][i0 + t] = ldsS[0][t] + ldsS[1][t] + ldsS[2][t] + ldsS[3][t];
  }
}

// ---------------- Kernel D: combine partials + normalize ----------------
__global__ __launch_bounds__(256) void comb_kernel(float* __restrict__ out) {
  const int u = blockIdx.x * 256 + threadIdx.x;  // float4 unit
  const int row = u >> 5;                        // 32 float4 per row
  const float s = g_spart[0][row] + g_spart[1][row] +
                  g_spart[2][row] + g_spart[3][row];
  const float inv = 1.0f / s;
  const f32x4 v = ((const f32x4*)g_part[0])[u] + ((const f32x4*)g_part[1])[u] +
                  ((const f32x4*)g_part[2])[u] + ((const f32x4*)g_part[3])[u];
  ((f32x4*)out)[u] = v * inv;
}

extern "C" void kernel_launch(void* const* d_in, const int* in_sizes, int n_in,
                              void* d_out, int out_size, void* d_ws, size_t ws_size,
                              hipStream_t stream) {
  const float* h = (const float*)d_in[0];
  const int* adj = (const int*)d_in[1];
  const float* W = (const float*)d_in[2];
  const float* a = (const float*)d_in[3];
  float* out = (float*)d_out;
  (void)d_ws; (void)ws_size;

  wh_kernel<<<dim3(N_NODES / 32), dim3(256), 0, stream>>>(h, W);
  f12_kernel<<<dim3(N_NODES / 2), dim3(256), 0, stream>>>(a);
  gat_attn_kernel<<<dim3(N_NODES / ROWS_PB, JSPLIT), dim3(256), 0, stream>>>(adj);
  comb_kernel<<<dim3(N_NODES * F_OUT / 4 / 256), dim3(256), 0, stream>>>(out);
}

// Round 4
// 420.754 us; speedup vs baseline: 1.4152x; 1.3564x over previous
//
#include <hip/hip_runtime.h>

// GAT layer, N=8192, F_IN=256, F_OUT=128.
// K1 wh: Wh = h@W (fp32 VALU) + WhT (f16 transposed [c][j]).  512 blocks.
// K2 f12: f1 = Wh@a1, f2 = Wh@a2.
// K3 attn: m97-style streaming loop. Block = 32 rows x 4096-j half (JSPLIT=2).
//   Per iter: adj 32x128 tile + f2 chunk DMA'd to LDS (global_load_lds, 16B,
//   rotation-swizzled rows so ds_read_b128 readback is conflict-free), B-frags
//   from L2/L3 direct to VGPR (issued BEFORE the DMA: vmcnt-FIFO waits on B
//   then don't drain the DMA), scores->f16->MFMA 16x16x32, psum via ones-MFMA.
//   Double-buffered LDS, waitcnt(0)+barrier per iter (m97 structure).
// K4 comb: (part0+part1)/(s0+s1).

#define N_NODES 8192
#define F_IN 256
#define F_OUT 128
#define RPB 32                      // rows per block
#define JCH 128                     // j per chunk (per iteration)
#define JSPLIT 2
#define JRANGE (N_NODES / JSPLIT)   // 4096
#define NCH (JRANGE / JCH)          // 32 iterations

typedef _Float16 half8 __attribute__((ext_vector_type(8)));
typedef float floatx4 __attribute__((ext_vector_type(4)));
typedef float f32x4 __attribute__((ext_vector_type(4)));

__device__ __align__(16) float g_Wh[N_NODES * F_OUT];                  // 4 MB
__device__ __align__(16) _Float16 g_WhT[(size_t)F_OUT * N_NODES];      // 2 MB
__device__ __align__(16) float g_f1[N_NODES];
__device__ __align__(16) float g_f2[N_NODES];
__device__ __align__(16) float g_part[JSPLIT][N_NODES * F_OUT];        // 8 MB
__device__ __align__(16) float g_spart[JSPLIT][N_NODES];               // 64 KB

#define GLD16(lds, gp)                                                        \
  __builtin_amdgcn_global_load_lds(                                           \
      (const __attribute__((address_space(1))) unsigned int*)(gp),            \
      (__attribute__((address_space(3))) unsigned int*)(lds), 16, 0, 0)

// ---------------- Kernel A: Wh = h @ W ----------------
__global__ __launch_bounds__(256, 2) void wh_kernel(
    const float* __restrict__ h, const float* __restrict__ W) {
  __shared__ float hT[F_IN][20];  // pad 20 keeps &hT[k][rg*8] 16B-aligned
  const int t = threadIdx.x;
  const int i0 = blockIdx.x * 16;
  {
    const int row = t >> 4;   // 0..15
    const int fu = t & 15;    // float4 unit
#pragma unroll
    for (int r = 0; r < 4; ++r) {
      const int ku = r * 16 + fu;  // 0..63
      const float4 v = *(const float4*)(h + (size_t)(i0 + row) * F_IN + ku * 4);
      hT[ku * 4 + 0][row] = v.x; hT[ku * 4 + 1][row] = v.y;
      hT[ku * 4 + 2][row] = v.z; hT[ku * 4 + 3][row] = v.w;
    }
  }
  __syncthreads();
  const int c = t & 127;
  const int rg = t >> 7;   // 8 rows per thread
  float acc[8];
#pragma unroll
  for (int r = 0; r < 8; ++r) acc[r] = 0.f;
#pragma unroll 8
  for (int k = 0; k < F_IN; ++k) {
    const float wv = W[k * F_OUT + c];
    const float4 x0 = *(const float4*)(&hT[k][rg * 8]);      // lane-uniform -> broadcast
    const float4 x1 = *(const float4*)(&hT[k][rg * 8 + 4]);
    acc[0] = fmaf(x0.x, wv, acc[0]); acc[1] = fmaf(x0.y, wv, acc[1]);
    acc[2] = fmaf(x0.z, wv, acc[2]); acc[3] = fmaf(x0.w, wv, acc[3]);
    acc[4] = fmaf(x1.x, wv, acc[4]); acc[5] = fmaf(x1.y, wv, acc[5]);
    acc[6] = fmaf(x1.z, wv, acc[6]); acc[7] = fmaf(x1.w, wv, acc[7]);
  }
#pragma unroll
  for (int r = 0; r < 8; ++r)
    g_Wh[(size_t)(i0 + rg * 8 + r) * F_OUT + c] = acc[r];
  union { _Float16 hh[8]; uint4 u4; } pk;
#pragma unroll
  for (int r = 0; r < 8; ++r) pk.hh[r] = (_Float16)acc[r];
  *(uint4*)(g_WhT + (size_t)c * N_NODES + i0 + rg * 8) = pk.u4;
}

// ---------------- Kernel B: f1 = Wh@a1, f2 = Wh@a2 ----------------
__global__ __launch_bounds__(256) void f12_kernel(const float* __restrict__ a) {
  const int t = threadIdx.x;
  const int row = blockIdx.x * 2 + (t >> 7);
  const int c = t & 127;
  const float wh = g_Wh[(size_t)row * F_OUT + c];
  float p1 = wh * a[c];
  float p2 = wh * a[F_OUT + c];
  for (int o = 32; o > 0; o >>= 1) {
    p1 += __shfl_down(p1, o, 64);
    p2 += __shfl_down(p2, o, 64);
  }
  __shared__ float s1[4], s2[4];
  const int w = t >> 6;
  if ((t & 63) == 0) { s1[w] = p1; s2[w] = p2; }
  __syncthreads();
  if ((t & 127) == 0) {
    g_f1[row] = s1[w] + s1[w + 1];
    g_f2[row] = s2[w] + s2[w + 1];
  }
}

// ---------------- Kernel C: fused attention (partials) ----------------
__device__ __forceinline__ float score_p(int a, float f2v, float f1r) {
  float s = f1r + f2v;
  s = fmaxf(s, 0.2f * s);  // leaky_relu, alpha=0.2<1
  float arg = (a > 0) ? fmaf(s, 1.44269504088896f, -16.0f) : -1.0e5f;
  return __builtin_amdgcn_exp2f(arg);  // masked -> 0; 2^-16 scale cancels in num/den
}

__global__ __launch_bounds__(256, 2) void gat_attn_kernel(const int* __restrict__ adj) {
  const int t = threadIdx.x;
  const int wave = t >> 6;
  const int lane = t & 63;
  const int mrow = lane & 15;
  const int quad = lane >> 4;
  const int i0 = blockIdx.x * RPB;
  const int js = blockIdx.y;
  const int jbase = js * JRANGE;

  __shared__ int ldsAdj[2][RPB * JCH];   // 2 x 16 KB, rotation-swizzled rows
  __shared__ float ldsF2[2][256];        // 2 x 1 KB (upper 128 floats = dummy)
  __shared__ float ldsO[RPB][F_OUT];     // 16 KB
  __shared__ float ldsS[4][RPB];

  // runtime C/D layout probe: D1[m][n]=m, D2[m][n]=n (self-correcting scatter)
  int rm[4], cm[4];
  {
    half8 a1f, b1f, a2f, b2f;
#pragma unroll
    for (int e = 0; e < 8; ++e) {
      a1f[e] = (_Float16)0; b1f[e] = (_Float16)0;
      a2f[e] = (_Float16)0; b2f[e] = (_Float16)0;
    }
    if (quad == 0) {
      a1f[0] = (_Float16)mrow; b1f[0] = (_Float16)1;
      a2f[0] = (_Float16)1;    b2f[0] = (_Float16)mrow;
    }
    floatx4 d1 = (floatx4)0.f, d2 = (floatx4)0.f;
    d1 = __builtin_amdgcn_mfma_f32_16x16x32_f16(a1f, b1f, d1, 0, 0, 0);
    d2 = __builtin_amdgcn_mfma_f32_16x16x32_f16(a2f, b2f, d2, 0, 0, 0);
#pragma unroll
    for (int r = 0; r < 4; ++r) { rm[r] = (int)d1[r]; cm[r] = (int)d2[r]; }
  }

  const float f1r0 = g_f1[i0 + mrow];
  const float f1r1 = g_f1[i0 + 16 + mrow];

  half8 ones;
#pragma unroll
  for (int e = 0; e < 8; ++e) ones[e] = (_Float16)1;

  floatx4 acc[2][8];
  floatx4 asum[2];
#pragma unroll
  for (int tl = 0; tl < 2; ++tl) {
    asum[tl] = (floatx4)0.f;
#pragma unroll
    for (int ct = 0; ct < 8; ++ct) acc[tl][ct] = (floatx4)0.f;
  }

  // DMA chunk cc into buffer bb. adj rows swizzled: row m, global 16B-unit u
  // lands at LDS slot ((u + m) & 31) of row m (slot = lane&31 in the DMA).
#define DMA(cc, bb) do {                                                      \
    _Pragma("unroll")                                                         \
    for (int R = 0; R < 4; ++R) {                                             \
      const int m = R * 8 + wave * 2 + (lane >> 5);                           \
      const int u = ((lane & 31) - m) & 31;                                   \
      const int* gp = adj + (size_t)(i0 + m) * N_NODES + jbase + (cc) * JCH + u * 4; \
      GLD16(&ldsAdj[bb][(R * 8 + wave * 2) * JCH], gp);                       \
    }                                                                         \
    if (wave == 0) {                                                          \
      int idx = jbase + (cc) * JCH + lane * 4;                                \
      idx = idx > (N_NODES - 4) ? (N_NODES - 4) : idx;                        \
      GLD16(&ldsF2[bb][0], g_f2 + idx);                                       \
    }                                                                         \
  } while (0)

  DMA(0, 0);
  __builtin_amdgcn_s_waitcnt(0);
  __syncthreads();

#pragma unroll 1
  for (int c = 0; c < NCH; ++c) {
    const int b = c & 1;
    const int jloc = wave * 32 + quad * 8;
    const int jglob = jbase + c * JCH + jloc;

    // B-frags first (vmcnt FIFO: their waits must not drain the DMA below)
    half8 bfr[8];
#pragma unroll
    for (int ct = 0; ct < 8; ++ct)
      bfr[ct] = *(const half8*)(g_WhT + (size_t)(ct * 16 + mrow) * N_NODES + jglob);

    if (c + 1 < NCH) DMA(c + 1, b ^ 1);

    // adj + f2 from LDS (swizzled readback)
    const int u0 = jloc >> 2;  // 16B-unit index within row
    const char* base = (const char*)&ldsAdj[b][0];
    const int4 A00 = *(const int4*)(base + mrow * 512 + (((u0 + mrow) & 31) << 4));
    const int4 A01 = *(const int4*)(base + mrow * 512 + (((u0 + 1 + mrow) & 31) << 4));
    const int m2 = mrow + 16;
    const int4 A10 = *(const int4*)(base + m2 * 512 + (((u0 + m2) & 31) << 4));
    const int4 A11 = *(const int4*)(base + m2 * 512 + (((u0 + 1 + m2) & 31) << 4));
    const float4 F0 = *(const float4*)&ldsF2[b][jloc];
    const float4 F1 = *(const float4*)&ldsF2[b][jloc + 4];

    half8 af0, af1;
    af0[0] = (_Float16)score_p(A00.x, F0.x, f1r0);
    af0[1] = (_Float16)score_p(A00.y, F0.y, f1r0);
    af0[2] = (_Float16)score_p(A00.z, F0.z, f1r0);
    af0[3] = (_Float16)score_p(A00.w, F0.w, f1r0);
    af0[4] = (_Float16)score_p(A01.x, F1.x, f1r0);
    af0[5] = (_Float16)score_p(A01.y, F1.y, f1r0);
    af0[6] = (_Float16)score_p(A01.z, F1.z, f1r0);
    af0[7] = (_Float16)score_p(A01.w, F1.w, f1r0);
    af1[0] = (_Float16)score_p(A10.x, F0.x, f1r1);
    af1[1] = (_Float16)score_p(A10.y, F0.y, f1r1);
    af1[2] = (_Float16)score_p(A10.z, F0.z, f1r1);
    af1[3] = (_Float16)score_p(A10.w, F0.w, f1r1);
    af1[4] = (_Float16)score_p(A11.x, F1.x, f1r1);
    af1[5] = (_Float16)score_p(A11.y, F1.y, f1r1);
    af1[6] = (_Float16)score_p(A11.z, F1.z, f1r1);
    af1[7] = (_Float16)score_p(A11.w, F1.w, f1r1);

#pragma unroll
    for (int ct = 0; ct < 8; ++ct) {
      acc[0][ct] = __builtin_amdgcn_mfma_f32_16x16x32_f16(af0, bfr[ct], acc[0][ct], 0, 0, 0);
      acc[1][ct] = __builtin_amdgcn_mfma_f32_16x16x32_f16(af1, bfr[ct], acc[1][ct], 0, 0, 0);
    }
    asum[0] = __builtin_amdgcn_mfma_f32_16x16x32_f16(af0, ones, asum[0], 0, 0, 0);
    asum[1] = __builtin_amdgcn_mfma_f32_16x16x32_f16(af1, ones, asum[1], 0, 0, 0);

    __builtin_amdgcn_s_waitcnt(0);  // drain DMA before buffer swap
    __syncthreads();
  }
#undef DMA

  // psum per row (all cols of asum equal; take the 4 probed rows per quad)
  if (mrow == 0) {
#pragma unroll
    for (int tl = 0; tl < 2; ++tl)
#pragma unroll
      for (int r = 0; r < 4; ++r)
        ldsS[wave][tl * 16 + rm[r]] = asum[tl][r];
  }
  // serialized wave-add of the 32x128 tile
  for (int w = 0; w < 4; ++w) {
    if (wave == w) {
#pragma unroll
      for (int tl = 0; tl < 2; ++tl)
#pragma unroll
        for (int ct = 0; ct < 8; ++ct)
#pragma unroll
          for (int r = 0; r < 4; ++r) {
            float* p = &ldsO[tl * 16 + rm[r]][ct * 16 + cm[r]];
            if (w == 0) *p = acc[tl][ct][r];
            else        *p += acc[tl][ct][r];
          }
    }
    __syncthreads();
  }
  {
    const int row = t >> 3;
    const int c0 = (t & 7) * 16;
    float* dst = g_part[js] + (size_t)(i0 + row) * F_OUT + c0;
#pragma unroll
    for (int q = 0; q < 4; ++q)
      *(f32x4*)(dst + q * 4) = *(const f32x4*)(&ldsO[row][c0 + q * 4]);
    if (t < RPB)
      g_spart[js][i0 + t] = ldsS[0][t] + ldsS[1][t] + ldsS[2][t] + ldsS[3][t];
  }
}

// ---------------- Kernel D: combine partials + normalize ----------------
__global__ __launch_bounds__(256) void comb_kernel(float* __restrict__ out) {
  const int u = blockIdx.x * 256 + threadIdx.x;  // float4 unit
  const int row = u >> 5;                        // 32 float4 per row
  const float s = g_spart[0][row] + g_spart[1][row];
  const f32x4 v = ((const f32x4*)g_part[0])[u] + ((const f32x4*)g_part[1])[u];
  ((f32x4*)out)[u] = v * (1.0f / s);
}

extern "C" void kernel_launch(void* const* d_in, const int* in_sizes, int n_in,
                              void* d_out, int out_size, void* d_ws, size_t ws_size,
                              hipStream_t stream) {
  const float* h = (const float*)d_in[0];
  const int* adj = (const int*)d_in[1];
  const float* W = (const float*)d_in[2];
  const float* a = (const float*)d_in[3];
  float* out = (float*)d_out;
  (void)d_ws; (void)ws_size;

  wh_kernel<<<dim3(N_NODES / 16), dim3(256), 0, stream>>>(h, W);
  f12_kernel<<<dim3(N_NODES / 2), dim3(256), 0, stream>>>(a);
  gat_attn_kernel<<<dim3(N_NODES / RPB, JSPLIT), dim3(256), 0, stream>>>(adj);
  comb_kernel<<<dim3(N_NODES * F_OUT / 4 / 256), dim3(256), 0, stream>>>(out);
}